// Round 13
// baseline (102.352 us; speedup 1.0000x reference)
//
#include <hip/hip_runtime.h>
#include <hip/hip_bf16.h>

typedef __bf16 bf16;
typedef __attribute__((ext_vector_type(8))) __bf16 bf16x8;
typedef __attribute__((ext_vector_type(4))) float floatx4;

#define PP 16
#define PPW 9
#define CFEAT 432      // C*P*PW = 3*16*9
#define EDIM 768
#define KDIM 768       // C*P*P = 3*256
#define NPAT 196
#define NBATCH 128
#define MROWS (NBATCH * NPAT)  // 25088

// prep_kernel block ranges
#define NB_W 2304                 // build_w: 768*3
#define NB_CLS 384                // cls: 128*768/256
#define NB_UNF 9408               // unfold: 25088*768/8/256
#define NB_PREP (NB_W + NB_CLS + NB_UNF)

__device__ inline void gload16(const void* g, void* l) {
  __builtin_amdgcn_global_load_lds(
      (const __attribute__((address_space(1))) void*)g,
      (__attribute__((address_space(3))) void*)l, 16, 0, 0);
}

// ---------------------------------------------------------------------------
// Kernel 1 (merged prep): build W_eff; cls row; patch-unfold x -> bf16 A.
// (unchanged — proven rounds 5..11)
// ---------------------------------------------------------------------------
__global__ __launch_bounds__(256) void prep_kernel(
    const float* __restrict__ x, const float* __restrict__ pw,
    const float* __restrict__ fwh, const float* __restrict__ fww,
    const float* __restrict__ cls, const float* __restrict__ pos,
    bf16* __restrict__ Wb, bf16* __restrict__ A, float* __restrict__ out) {
  const int blk = blockIdx.x;
  const int t = threadIdx.x;

  if (blk >= NB_W + NB_CLS) {  // ---- unfold (bulk path) ----
    const int i = (blk - NB_W - NB_CLS) * 256 + t;  // < 2408448
    const int w8 = i % 28;
    const int tmp = i / 28;
    const int h = tmp % 224;
    const int tmp2 = tmp / 224;
    const int c = tmp2 % 3;
    const int b = tmp2 / 3;
    const float4 f0 = *reinterpret_cast<const float4*>(x + (size_t)i * 8);
    const float4 f1 = *reinterpret_cast<const float4*>(x + (size_t)i * 8 + 4);
    bf16x8 v;
    v[0] = (bf16)f0.x; v[1] = (bf16)f0.y; v[2] = (bf16)f0.z; v[3] = (bf16)f0.w;
    v[4] = (bf16)f1.x; v[5] = (bf16)f1.y; v[6] = (bf16)f1.z; v[7] = (bf16)f1.w;
    const int row = b * NPAT + (h >> 4) * 14 + (w8 >> 1);
    const int k = c * 256 + (h & 15) * 16 + (w8 & 1) * 8;
    *reinterpret_cast<bf16x8*>(A + (size_t)row * KDIM + k) = v;
  } else if (blk < NB_W) {  // ---- build W_eff ----
    __shared__ float s_pw[144];
    __shared__ float s_fh[16];
    __shared__ float s_fw[9];
    __shared__ float s_cos[16];
    const int e = blk / 3;
    const int c = blk % 3;
    if (t < 144) s_pw[t] = pw[e * CFEAT + c * 144 + t];
    if (t < 16) {
      s_fh[t] = fwh[t];
      s_cos[t] = cosf((float)t * 0.39269908169872414f);  // 2*pi/16
    }
    if (t < 9) s_fw[t] = fww[t];
    __syncthreads();
    const int h = t >> 4, w = t & 15;
    float acc = 0.f;
#pragma unroll
    for (int u = 0; u < 16; ++u) {
      const float fh = s_fh[u];
      const int uh = (u * h) & 15;
#pragma unroll
      for (int v = 0; v < 9; ++v) {
        acc += s_pw[u * 9 + v] * s_fw[v] * s_cos[(uh + v * w) & 15] * fh;
      }
    }
    Wb[e * KDIM + c * 256 + t] = (bf16)(acc * 0.0625f);
  } else {  // ---- cls row ----
    const int idx = (blk - NB_W) * 256 + t;  // < 128*768
    const int b = idx / 768;
    const int e = idx - b * 768;
    out[(size_t)b * 197 * 768 + e] = cls[e] + pos[e];
  }
}

// ---------------------------------------------------------------------------
// Kernel 2: r5's sync discipline with FAT PER-WAVE TILES.
// Block tile 256x128, 4 waves (256 thr), per-wave 128x64 (8x4 MFMA frags).
// LDS bytes/FLOP drops 1.33x (1/M+1/N: 1/32 -> 3/128); barrier-steps per
// output FLOP halve vs r5.  BK=32, dbuf LDS 48 KB (A 2x16KB, B 2x8KB).
// Staging: 6x global_load_lds width-16 per thread (A 4, B 2), linear LDS.
// Per iter: STAGE(next) -> COMPUTE(cur) -> __syncthreads (r5 discipline,
// no raw barriers, no manual vmcnt — race-free class).
// Grid 588 = 98 mt x 6 nt, m204 bijective XCD swizzle (verified r8):
// 6 consecutive wgid share mt -> A-panel fetched once per XCD.
// ---------------------------------------------------------------------------
__global__ __launch_bounds__(256) void gemm_fat_kernel(
    const bf16* __restrict__ A, const bf16* __restrict__ Wb,
    const float* __restrict__ pb, const float* __restrict__ pos,
    float* __restrict__ out) {
  __shared__ __align__(16) bf16 sA[2][256 * 32];  // 32 KB
  __shared__ __align__(16) bf16 sB[2][128 * 32];  // 16 KB

  const int bid = blockIdx.x;  // 0..587 ; 588 = 8*73+4 -> m204 bijective
  const int xcd = bid & 7;
  const int idx = bid >> 3;
  const int wgid = (xcd < 4 ? xcd * 74 : 296 + (xcd - 4) * 73) + idx;
  const int mt = wgid / 6;       // 0..97
  const int nt = wgid - mt * 6;  // 0..5

  const int t = threadIdx.x;
  const int l = t & 63;
  const int wv = t >> 6;   // 0..3
  const int wm = wv >> 1;  // 0..1 : 128-row half
  const int wn = wv & 1;   // 0..1 : 64-col half
  const int lr = l & 15, lq = l >> 4;

  // staging: chunk c = j*256 + t -> row c>>2, k-chunk (t&3)*8 ; LDS linear
  const bf16* gA0 = A + (size_t)(mt * 256 + (t >> 2)) * KDIM + (t & 3) * 8;
  const bf16* gB0 = Wb + (size_t)(nt * 128 + (t >> 2)) * KDIM + (t & 3) * 8;
  const size_t rstep = (size_t)64 * KDIM;
  const int lbase = wv * 512;  // wave-uniform; HW adds lane*16B

#define STAGE(buf, kts)                                      \
  do {                                                       \
    const int ko = (kts)*32;                                 \
    gload16(gA0 + ko, &sA[buf][lbase]);                      \
    gload16(gA0 + rstep + ko, &sA[buf][2048 + lbase]);       \
    gload16(gA0 + 2 * rstep + ko, &sA[buf][4096 + lbase]);   \
    gload16(gA0 + 3 * rstep + ko, &sA[buf][6144 + lbase]);   \
    gload16(gB0 + ko, &sB[buf][lbase]);                      \
    gload16(gB0 + rstep + ko, &sB[buf][2048 + lbase]);       \
  } while (0)

  floatx4 acc[8][4];
#pragma unroll
  for (int i = 0; i < 8; ++i)
#pragma unroll
    for (int j = 0; j < 4; ++j) acc[i][j] = (floatx4){0.f, 0.f, 0.f, 0.f};

#define COMPUTE(buf)                                                         \
  do {                                                                       \
    bf16x8 af[8], bfr[4];                                                    \
    _Pragma("unroll") for (int mi = 0; mi < 8; ++mi) {                       \
      const int r = wm * 128 + mi * 16 + lr;                                 \
      af[mi] = *reinterpret_cast<const bf16x8*>(&sA[buf][r * 32 + lq * 8]);  \
    }                                                                        \
    _Pragma("unroll") for (int ni = 0; ni < 4; ++ni) {                       \
      const int r = wn * 64 + ni * 16 + lr;                                  \
      bfr[ni] = *reinterpret_cast<const bf16x8*>(&sB[buf][r * 32 + lq * 8]); \
    }                                                                        \
    _Pragma("unroll") for (int mi = 0; mi < 8; ++mi)                         \
        _Pragma("unroll") for (int ni = 0; ni < 4; ++ni) acc[mi][ni] =       \
            __builtin_amdgcn_mfma_f32_16x16x32_bf16(af[mi], bfr[ni],         \
                                                    acc[mi][ni], 0, 0, 0);   \
  } while (0)

  STAGE(0, 0);
  __syncthreads();
  int cur = 0;
  for (int kt = 0; kt < 23; ++kt) {
    STAGE(cur ^ 1, kt + 1);  // prefetch next tile (in flight thru compute)
    COMPUTE(cur);
    __syncthreads();  // full drain AFTER compute — r5 discipline
    cur ^= 1;
  }
  COMPUTE(cur);
#undef STAGE
#undef COMPUTE

  // epilogue: out[b][1+n][e] = acc + proj_b[e] + pos_emb[1+n][e]
  float pbv[4];
#pragma unroll
  for (int ni = 0; ni < 4; ++ni)
    pbv[ni] = pb[nt * 128 + wn * 64 + ni * 16 + lr];

#pragma unroll
  for (int mi = 0; mi < 8; ++mi) {
#pragma unroll
    for (int j = 0; j < 4; ++j) {
      const unsigned m = wm * 128 + mi * 16 + lq * 4 + j;
      const unsigned Rr = mt * 256u + m;
      const unsigned b2 = Rr / 196u;
      const unsigned np2 = Rr - b2 * 196u;
      float* orow = out + ((size_t)b2 * 197 + 1 + np2) * 768;
      const float* prow = pos + (size_t)(1 + np2) * 768;
#pragma unroll
      for (int ni = 0; ni < 4; ++ni) {
        const int e = nt * 128 + wn * 64 + ni * 16 + lr;
        orow[e] = acc[mi][ni][j] + pbv[ni] + prow[e];
      }
    }
  }
}

extern "C" void kernel_launch(void* const* d_in, const int* in_sizes, int n_in,
                              void* d_out, int out_size, void* d_ws,
                              size_t ws_size, hipStream_t stream) {
  const float* x = (const float*)d_in[0];
  const float* fwh = (const float*)d_in[1];
  const float* fww = (const float*)d_in[2];
  const float* proj_w = (const float*)d_in[3];
  const float* proj_b = (const float*)d_in[4];
  const float* cls = (const float*)d_in[5];
  const float* pos = (const float*)d_in[6];
  float* out = (float*)d_out;

  const size_t needW = (size_t)EDIM * KDIM * sizeof(bf16);  // 1.18 MB
  bf16* Wb = (bf16*)d_ws;
  bf16* A = (bf16*)((char*)d_ws + needW);  // 38.5 MB

  prep_kernel<<<NB_PREP, 256, 0, stream>>>(x, proj_w, fwh, fww, cls, pos, Wb,
                                           A, out);
  gemm_fat_kernel<<<588, 256, 0, stream>>>(A, Wb, proj_b, pos, out);
}